// Round 1
// baseline (999.071 us; speedup 1.0000x reference)
//
#include <hip/hip_runtime.h>
#include <cmath>

#define B_ 32
#define N_ 197
#define C_ 768
#define H_ 12
#define D_ 64
#define M_ (B_*N_)        // 6304
#define K3_ (3*C_)        // 2304
#define NN_ (N_*N_)       // 38809
#define BH_ (B_*H_)       // 384
#define SCALE 0.125f

// ---------------------------------------------------------------------------
// K1: X[M,768] @ Wqkv[768,2304] -> scatter to q,k,v each [B,H,N,D]
// 64x64 tile, BK=16, 256 threads, 4x4 register micro-tile, float4 LDS reads.
__global__ __launch_bounds__(256) void gemm_qkv(const float* __restrict__ X,
        const float* __restrict__ W, float* __restrict__ q,
        float* __restrict__ k, float* __restrict__ v) {
    __shared__ __align__(16) float As[16][68];   // As[kk][m]
    __shared__ __align__(16) float Bs[16][68];   // Bs[kk][n]
    const int tid = threadIdx.x;
    const int tx = tid & 15, ty = tid >> 4;
    const int row0 = blockIdx.x * 64;
    const int col0 = blockIdx.y * 64;
    float acc[4][4] = {};
    for (int k0 = 0; k0 < 768; k0 += 16) {
        {   // A load: 64 rows x 16 k (float4 per thread)
            int m  = tid >> 2;      // 0..63
            int qq = tid & 3;       // 0..3
            int r  = row0 + m;
            float4 a = (r < M_) ? *(const float4*)&X[(size_t)r*768 + k0 + qq*4]
                                : make_float4(0.f,0.f,0.f,0.f);
            As[qq*4+0][m] = a.x; As[qq*4+1][m] = a.y;
            As[qq*4+2][m] = a.z; As[qq*4+3][m] = a.w;
        }
        {   // B load: 16 k x 64 cols (float4 per thread)
            int kk = tid >> 4;          // 0..15
            int n4 = (tid & 15) * 4;    // 0..60
            *(float4*)&Bs[kk][n4] =
                *(const float4*)&W[(size_t)(k0+kk)*K3_ + col0 + n4];
        }
        __syncthreads();
        #pragma unroll
        for (int kk = 0; kk < 16; ++kk) {
            float4 a4 = *(float4*)&As[kk][ty*4];
            float4 b4 = *(float4*)&Bs[kk][tx*4];
            float a[4] = {a4.x, a4.y, a4.z, a4.w};
            float b[4] = {b4.x, b4.y, b4.z, b4.w};
            #pragma unroll
            for (int i = 0; i < 4; i++)
                #pragma unroll
                for (int j = 0; j < 4; j++) acc[i][j] += a[i] * b[j];
        }
        __syncthreads();
    }
    // scatter: col -> (which, h, d). Tile is 64-wide, aligned: single (which,h).
    const int c0    = col0 + tx*4;
    const int which = c0 / 768;
    const int rem   = c0 - which*768;
    const int h     = rem >> 6;
    const int dbase = rem & 63;
    float* dst = (which == 0) ? q : ((which == 1) ? k : v);
    #pragma unroll
    for (int i = 0; i < 4; i++) {
        int r = row0 + ty*4 + i;
        if (r >= M_) break;
        int bb = r / N_;
        int n  = r - bb * N_;
        *(float4*)&dst[(((size_t)(bb*H_ + h))*N_ + n)*64 + dbase] =
            make_float4(acc[i][0], acc[i][1], acc[i][2], acc[i][3]);
    }
}

// ---------------------------------------------------------------------------
// K2: batched S[bh] = SCALE * A[bh] @ B[bh]^T  (A,B: [N,64] per bh)
// grid (7, BH). B matrix staged in LDS; 32-row tile; 8 rows x 4 cols / thread.
__global__ __launch_bounds__(256) void qkt_kernel(const float* __restrict__ A,
        const float* __restrict__ Bm, float* __restrict__ S) {
    __shared__ float Bl[197*65];
    __shared__ float Al[32*65];
    const int tid = threadIdx.x;
    const int bh  = blockIdx.y;
    const int r0  = blockIdx.x * 32;
    const float* Ab = A  + (size_t)bh * N_ * D_;
    const float* Bb = Bm + (size_t)bh * N_ * D_;
    for (int i = tid; i < N_*D_; i += 256) {
        int m = i >> 6, kk = i & 63;
        Bl[m*65 + kk] = Bb[i];
    }
    for (int i = tid; i < 32*64; i += 256) {
        int m = i >> 6, kk = i & 63;
        int r = r0 + m;
        Al[m*65 + kk] = (r < N_) ? Ab[(size_t)r*64 + kk] : 0.f;
    }
    __syncthreads();
    const int w = tid >> 6, l = tid & 63;
    int  mc[4];
    bool mv[4];
    #pragma unroll
    for (int c = 0; c < 4; c++) {
        int m = l + 64*c;
        mv[c] = (m < N_);
        mc[c] = mv[c] ? m : (N_-1);
    }
    float acc[8][4] = {};
    for (int kk = 0; kk < 64; ++kk) {
        float a[8];
        #pragma unroll
        for (int i = 0; i < 8; i++) a[i] = Al[(w*8 + i)*65 + kk];
        float b[4];
        #pragma unroll
        for (int c = 0; c < 4; c++) b[c] = Bl[mc[c]*65 + kk];
        #pragma unroll
        for (int i = 0; i < 8; i++)
            #pragma unroll
            for (int c = 0; c < 4; c++) acc[i][c] += a[i] * b[c];
    }
    #pragma unroll
    for (int i = 0; i < 8; i++) {
        int r = r0 + w*8 + i;
        if (r >= N_) break;
        float* Srow = S + ((size_t)bh*N_ + r) * N_;
        #pragma unroll
        for (int c = 0; c < 4; c++)
            if (mv[c]) Srow[l + 64*c] = acc[i][c] * SCALE;
    }
}

// ---------------------------------------------------------------------------
// K3: in-place row softmax over last dim (rows of length 197). 4 rows/block.
__global__ __launch_bounds__(256) void softmax_inplace(float* __restrict__ S) {
    const int row = blockIdx.x*4 + (threadIdx.x >> 6);
    const int l   = threadIdx.x & 63;
    float* p = S + (size_t)row * N_;
    float vv[4];
    float mx = -1e30f;
    #pragma unroll
    for (int c = 0; c < 4; c++) {
        int m = l + 64*c;
        vv[c] = (m < N_) ? p[m] : -1e30f;
        mx = fmaxf(mx, vv[c]);
    }
    #pragma unroll
    for (int off = 32; off; off >>= 1) mx = fmaxf(mx, __shfl_xor(mx, off));
    float s = 0.f;
    #pragma unroll
    for (int c = 0; c < 4; c++) {
        int m = l + 64*c;
        if (m < N_) { vv[c] = __expf(vv[c] - mx); s += vv[c]; }
    }
    #pragma unroll
    for (int off = 32; off; off >>= 1) s += __shfl_xor(s, off);
    const float inv = 1.f / s;
    #pragma unroll
    for (int c = 0; c < 4; c++) {
        int m = l + 64*c;
        if (m < N_) p[m] = vv[c] * inv;
    }
}

// ---------------------------------------------------------------------------
// K4: probs = softmax(conv_l(scores)) fused, one block per (b,n).
__global__ __launch_bounds__(256) void convl_softmax(const float* __restrict__ SC,
        const float* __restrict__ wl, float* __restrict__ PR) {
    __shared__ float raw[12*200];
    __shared__ float mixed[12*200];
    __shared__ float wls[144];
    const int tid = threadIdx.x;
    const int b = blockIdx.x / N_;
    const int n = blockIdx.x - b * N_;
    if (tid < 144) wls[tid] = wl[tid];
    for (int i = tid; i < 12*N_; i += 256) {
        int h = i / N_, m = i - h*N_;
        raw[h*200 + m] = SC[(((size_t)(b*12 + h))*N_ + n)*N_ + m];
    }
    __syncthreads();
    for (int i = tid; i < 12*N_; i += 256) {
        int o = i / N_, m = i - o*N_;
        float s = 0.f;
        #pragma unroll
        for (int h = 0; h < 12; h++) s += wls[o*12 + h] * raw[h*200 + m];
        mixed[o*200 + m] = s;
    }
    __syncthreads();
    const int w = tid >> 6, l = tid & 63;
    for (int j = 0; j < 3; j++) {
        const int o = w*3 + j;
        float vv[4];
        float mx = -1e30f;
        #pragma unroll
        for (int c = 0; c < 4; c++) {
            int m = l + 64*c;
            vv[c] = (m < N_) ? mixed[o*200 + m] : -1e30f;
            mx = fmaxf(mx, vv[c]);
        }
        #pragma unroll
        for (int off = 32; off; off >>= 1) mx = fmaxf(mx, __shfl_xor(mx, off));
        float s = 0.f;
        #pragma unroll
        for (int c = 0; c < 4; c++) {
            int m = l + 64*c;
            if (m < N_) { vv[c] = __expf(vv[c] - mx); s += vv[c]; }
        }
        #pragma unroll
        for (int off = 32; off; off >>= 1) s += __shfl_xor(s, off);
        const float inv = 1.f / s;
        float* Prow = PR + (((size_t)(b*12 + o))*N_ + n)*N_;
        #pragma unroll
        for (int c = 0; c < 4; c++) {
            int m = l + 64*c;
            if (m < N_) Prow[m] = vv[c] * inv;
        }
    }
}

// ---------------------------------------------------------------------------
// K5: attn_w = conv_w(probs) — 12x12 head mix, elementwise over (n,m).
__global__ __launch_bounds__(256) void convw_kernel(const float* __restrict__ PR,
        const float* __restrict__ ww, float* __restrict__ AW) {
    __shared__ float wws[144];
    const int tid = threadIdx.x;
    if (tid < 144) wws[tid] = ww[tid];
    __syncthreads();
    const int b = blockIdx.y;
    const long long p = (long long)blockIdx.x * 256 + tid;
    if (p >= NN_) return;
    float in[12];
    #pragma unroll
    for (int h = 0; h < 12; h++) in[h] = PR[((size_t)(b*12 + h))*NN_ + p];
    #pragma unroll
    for (int o = 0; o < 12; o++) {
        float s = 0.f;
        #pragma unroll
        for (int h = 0; h < 12; h++) s += wws[o*12 + h] * in[h];
        AW[((size_t)(b*12 + o))*NN_ + p] = s;
    }
}

// ---------------------------------------------------------------------------
// K6: out_pre[b,n,h,d] = sum_m attn_w[b,h,n,m] * v[b,h,m,d]. v in LDS.
__global__ __launch_bounds__(256) void av_kernel(const float* __restrict__ AW,
        const float* __restrict__ V, float* __restrict__ OP) {
    __shared__ float Vl[197*64];
    const int tid = threadIdx.x;
    const int bh  = blockIdx.y;
    const int r0  = blockIdx.x * 32;
    const float* Vb = V + (size_t)bh * N_ * D_;
    for (int i = tid; i < N_*D_; i += 256) Vl[i] = Vb[i];
    __syncthreads();
    const int w = tid >> 6, l = tid & 63;
    const float* Arow[8];
    #pragma unroll
    for (int i = 0; i < 8; i++) {
        int r = r0 + w*8 + i;
        if (r >= N_) r = N_ - 1;
        Arow[i] = AW + ((size_t)bh*N_ + r) * N_;
    }
    float acc[8] = {};
    for (int m = 0; m < N_; m++) {
        float bv = Vl[m*64 + l];
        #pragma unroll
        for (int i = 0; i < 8; i++) acc[i] += Arow[i][m] * bv;
    }
    const int b = bh / 12, h = bh - b*12;
    #pragma unroll
    for (int i = 0; i < 8; i++) {
        int r = r0 + w*8 + i;
        if (r < N_)
            OP[((size_t)(b*N_ + r))*C_ + h*64 + l] = acc[i];
    }
}

// ---------------------------------------------------------------------------
// K7: Y[M,768] = OP[M,768] @ Wp[768,768] + bias
__global__ __launch_bounds__(256) void gemm_proj(const float* __restrict__ X,
        const float* __restrict__ W, const float* __restrict__ bias,
        float* __restrict__ Y) {
    __shared__ __align__(16) float As[16][68];
    __shared__ __align__(16) float Bs[16][68];
    const int tid = threadIdx.x;
    const int tx = tid & 15, ty = tid >> 4;
    const int row0 = blockIdx.x * 64;
    const int col0 = blockIdx.y * 64;
    float acc[4][4] = {};
    for (int k0 = 0; k0 < 768; k0 += 16) {
        {
            int m  = tid >> 2;
            int qq = tid & 3;
            int r  = row0 + m;
            float4 a = (r < M_) ? *(const float4*)&X[(size_t)r*768 + k0 + qq*4]
                                : make_float4(0.f,0.f,0.f,0.f);
            As[qq*4+0][m] = a.x; As[qq*4+1][m] = a.y;
            As[qq*4+2][m] = a.z; As[qq*4+3][m] = a.w;
        }
        {
            int kk = tid >> 4;
            int n4 = (tid & 15) * 4;
            *(float4*)&Bs[kk][n4] =
                *(const float4*)&W[(size_t)(k0+kk)*768 + col0 + n4];
        }
        __syncthreads();
        #pragma unroll
        for (int kk = 0; kk < 16; ++kk) {
            float4 a4 = *(float4*)&As[kk][ty*4];
            float4 b4 = *(float4*)&Bs[kk][tx*4];
            float a[4] = {a4.x, a4.y, a4.z, a4.w};
            float b[4] = {b4.x, b4.y, b4.z, b4.w};
            #pragma unroll
            for (int i = 0; i < 4; i++)
                #pragma unroll
                for (int j = 0; j < 4; j++) acc[i][j] += a[i] * b[j];
        }
        __syncthreads();
    }
    const int c0 = col0 + tx*4;
    const float4 b4 = *(const float4*)&bias[c0];
    #pragma unroll
    for (int i = 0; i < 4; i++) {
        int r = row0 + ty*4 + i;
        if (r >= M_) break;
        *(float4*)&Y[(size_t)r*768 + c0] =
            make_float4(acc[i][0]+b4.x, acc[i][1]+b4.y,
                        acc[i][2]+b4.z, acc[i][3]+b4.w);
    }
}

// ---------------------------------------------------------------------------
extern "C" void kernel_launch(void* const* d_in, const int* in_sizes, int n_in,
                              void* d_out, int out_size, void* d_ws, size_t ws_size,
                              hipStream_t stream) {
    const float* x      = (const float*)d_in[0];
    const float* w_qkv  = (const float*)d_in[1];
    const float* w_proj = (const float*)d_in[2];
    const float* b_proj = (const float*)d_in[3];
    const float* w_cl   = (const float*)d_in[4];
    const float* w_cw   = (const float*)d_in[5];

    float* out    = (float*)d_out;                    // [B,N,C]
    float* scores = out    + (size_t)M_ * C_;         // [B,H,N,N]
    float* probs  = scores + (size_t)BH_ * NN_;       // [B,H,N,N]
    float* vmap   = probs  + (size_t)BH_ * NN_;       // [B,H,N,N]

    float* ws      = (float*)d_ws;
    const size_t QS = (size_t)BH_ * N_ * D_;          // 4,841,472
    float* q       = ws;
    float* k       = ws + QS;
    float* v       = ws + 2*QS;
    float* aw      = ws + 3*QS;                       // [B,H,N,N]
    float* out_pre = q;                               // q dead after K2a

    gemm_qkv      <<<dim3(99, 36),  256, 0, stream>>>(x, w_qkv, q, k, v);
    qkt_kernel    <<<dim3(7, BH_),  256, 0, stream>>>(q, k, scores);
    qkt_kernel    <<<dim3(7, BH_),  256, 0, stream>>>(v, v, vmap);
    softmax_inplace<<<(BH_*N_)/4,   256, 0, stream>>>(vmap);
    convl_softmax <<<M_,            256, 0, stream>>>(scores, w_cl, probs);
    convw_kernel  <<<dim3(152, B_), 256, 0, stream>>>(probs, w_cw, aw);
    av_kernel     <<<dim3(7, BH_),  256, 0, stream>>>(aw, v, out_pre);
    gemm_proj     <<<dim3(99, 12),  256, 0, stream>>>(out_pre, w_proj, b_proj, out);
}

// Round 2
// 687.559 us; speedup vs baseline: 1.4531x; 1.4531x over previous
//
#include <hip/hip_runtime.h>
#include <cmath>

#define B_ 32
#define N_ 197
#define C_ 768
#define H_ 12
#define D_ 64
#define M_ (B_*N_)        // 6304
#define MPAD_ 6400        // padded rows for 128-tiles
#define K3_ (3*C_)        // 2304
#define NN_ (N_*N_)       // 38809
#define BH_ (B_*H_)       // 384
#define SCALE 0.125f

typedef __bf16 bf16x8 __attribute__((ext_vector_type(8)));
typedef __bf16 bf16x4 __attribute__((ext_vector_type(4)));
typedef float  f32x4  __attribute__((ext_vector_type(4)));

__device__ __forceinline__ void gl_lds16(const void* g, void* l) {
    __builtin_amdgcn_global_load_lds(
        (const __attribute__((address_space(1))) void*)g,
        (__attribute__((address_space(3))) void*)l,
        16, 0, 0);
}

// ---------------------------------------------------------------------------
// cast X [6304,768] f32 -> Xb [6400,768] bf16 (pad rows zeroed)
__global__ __launch_bounds__(256) void cast_x_kernel(const float* __restrict__ X,
        __bf16* __restrict__ Xb) {
    const long long i = ((long long)blockIdx.x * 256 + threadIdx.x) * 4;
    if (i >= (long long)MPAD_ * 768) return;
    bf16x4 o;
    if (i < (long long)M_ * 768) {
        float4 f = *(const float4*)&X[i];
        o.x = (__bf16)f.x; o.y = (__bf16)f.y; o.z = (__bf16)f.z; o.w = (__bf16)f.w;
    } else {
        o.x = o.y = o.z = o.w = (__bf16)0.f;
    }
    *(bf16x4*)&Xb[i] = o;
}

// ---------------------------------------------------------------------------
// transpose-cast W [R,Ccols] f32 -> Wt [Ccols,R] bf16
__global__ __launch_bounds__(256) void transpose_cast(const float* __restrict__ W,
        __bf16* __restrict__ Wt, int R, int Ccols) {
    __shared__ float t[32][33];
    const int c0 = blockIdx.x * 32;   // col tile (becomes row of Wt)
    const int r0 = blockIdx.y * 32;
    const int tx = threadIdx.x & 31, ty = threadIdx.x >> 5;  // ty 0..7
    #pragma unroll
    for (int i = ty; i < 32; i += 8)
        t[i][tx] = W[(size_t)(r0 + i) * Ccols + c0 + tx];
    __syncthreads();
    #pragma unroll
    for (int i = ty; i < 32; i += 8)
        Wt[(size_t)(c0 + i) * R + r0 + tx] = (__bf16)t[tx][i];
}

// ---------------------------------------------------------------------------
// MFMA GEMM: D[M,2304] = Xb[M,768] @ Wt[2304,768]^T, scatter to q,k,v fp32.
// 128x128 tile, BK=32, 256 thr = 4 waves (2x2), 4x4 16x16x32 frags per wave.
__global__ __launch_bounds__(256) void mfma_qkv(const __bf16* __restrict__ Xb,
        const __bf16* __restrict__ Wt, float* __restrict__ q,
        float* __restrict__ k, float* __restrict__ v) {
    __shared__ __bf16 As[128*32];
    __shared__ __bf16 Bs[128*32];
    const int tid = threadIdx.x;
    const int wv = tid >> 6, ln = tid & 63;
    const int R0 = blockIdx.x * 128;
    const int C0 = blockIdx.y * 128;
    const int wm = wv >> 1, wn = wv & 1;
    const int arow = ln >> 2, akg = ln & 3;
    f32x4 acc[4][4] = {};
    for (int k0 = 0; k0 < 768; k0 += 32) {
        __syncthreads();
        #pragma unroll
        for (int s = 0; s < 2; s++) {
            const int seg = wv + s*4;                 // 0..7
            const int row = seg*16 + arow;            // 0..127
            gl_lds16(Xb + (size_t)(R0 + row)*768 + k0 + akg*8,
                     (char*)As + seg*1024 + ln*16);
            gl_lds16(Wt + (size_t)(C0 + row)*768 + k0 + akg*8,
                     (char*)Bs + seg*1024 + ln*16);
        }
        __syncthreads();
        bf16x8 af[4], bfr[4];
        #pragma unroll
        for (int t = 0; t < 4; t++) {
            af[t]  = *(const bf16x8*)((const char*)As +
                        (wm*64 + t*16 + (ln & 15))*64 + (ln >> 4)*16);
            bfr[t] = *(const bf16x8*)((const char*)Bs +
                        (wn*64 + t*16 + (ln & 15))*64 + (ln >> 4)*16);
        }
        #pragma unroll
        for (int i = 0; i < 4; i++)
            #pragma unroll
            for (int j = 0; j < 4; j++)
                acc[i][j] = __builtin_amdgcn_mfma_f32_16x16x32_bf16(
                                af[i], bfr[j], acc[i][j], 0, 0, 0);
    }
    const int lr = (ln >> 4) * 4;
    const int lc = ln & 15;
    #pragma unroll
    for (int j = 0; j < 4; j++) {
        const int c = C0 + wn*64 + j*16 + lc;         // 0..2303
        const int which = c / 768;
        const int rem = c - which*768;
        const int h = rem >> 6, d = rem & 63;
        float* dst = (which == 0) ? q : ((which == 1) ? k : v);
        #pragma unroll
        for (int i = 0; i < 4; i++) {
            #pragma unroll
            for (int rr = 0; rr < 4; rr++) {
                const int r = R0 + wm*64 + i*16 + lr + rr;
                if (r < M_) {
                    const int bb = r / N_, n = r - bb*N_;
                    dst[(((size_t)(bb*H_ + h))*N_ + n)*64 + d] = acc[i][j][rr];
                }
            }
        }
    }
}

// ---------------------------------------------------------------------------
// MFMA GEMM: out[M,768] = OPb[M,768] @ Wpt[768,768]^T + bias
__global__ __launch_bounds__(256) void mfma_proj(const __bf16* __restrict__ Ab,
        const __bf16* __restrict__ Wt, const float* __restrict__ bias,
        float* __restrict__ Y) {
    __shared__ __bf16 As[128*32];
    __shared__ __bf16 Bs[128*32];
    const int tid = threadIdx.x;
    const int wv = tid >> 6, ln = tid & 63;
    const int R0 = blockIdx.x * 128;
    const int C0 = blockIdx.y * 128;
    const int wm = wv >> 1, wn = wv & 1;
    const int arow = ln >> 2, akg = ln & 3;
    f32x4 acc[4][4] = {};
    for (int k0 = 0; k0 < 768; k0 += 32) {
        __syncthreads();
        #pragma unroll
        for (int s = 0; s < 2; s++) {
            const int seg = wv + s*4;
            const int row = seg*16 + arow;
            gl_lds16(Ab + (size_t)(R0 + row)*768 + k0 + akg*8,
                     (char*)As + seg*1024 + ln*16);
            gl_lds16(Wt + (size_t)(C0 + row)*768 + k0 + akg*8,
                     (char*)Bs + seg*1024 + ln*16);
        }
        __syncthreads();
        bf16x8 af[4], bfr[4];
        #pragma unroll
        for (int t = 0; t < 4; t++) {
            af[t]  = *(const bf16x8*)((const char*)As +
                        (wm*64 + t*16 + (ln & 15))*64 + (ln >> 4)*16);
            bfr[t] = *(const bf16x8*)((const char*)Bs +
                        (wn*64 + t*16 + (ln & 15))*64 + (ln >> 4)*16);
        }
        #pragma unroll
        for (int i = 0; i < 4; i++)
            #pragma unroll
            for (int j = 0; j < 4; j++)
                acc[i][j] = __builtin_amdgcn_mfma_f32_16x16x32_bf16(
                                af[i], bfr[j], acc[i][j], 0, 0, 0);
    }
    const int lr = (ln >> 4) * 4;
    const int lc = ln & 15;
    #pragma unroll
    for (int j = 0; j < 4; j++) {
        const int c = C0 + wn*64 + j*16 + lc;   // < 768
        const float bv = bias[c];
        #pragma unroll
        for (int i = 0; i < 4; i++) {
            #pragma unroll
            for (int rr = 0; rr < 4; rr++) {
                const int r = R0 + wm*64 + i*16 + lr + rr;
                if (r < M_) Y[(size_t)r*768 + c] = acc[i][j][rr] + bv;
            }
        }
    }
}

// ---------------------------------------------------------------------------
// K2: batched S[bh] = SCALE * A[bh] @ B[bh]^T  (A,B: [N,64] per bh)
__global__ __launch_bounds__(256) void qkt_kernel(const float* __restrict__ A,
        const float* __restrict__ Bm, float* __restrict__ S) {
    __shared__ float Bl[197*65];
    __shared__ float Al[32*65];
    const int tid = threadIdx.x;
    const int bh  = blockIdx.y;
    const int r0  = blockIdx.x * 32;
    const float* Ab = A  + (size_t)bh * N_ * D_;
    const float* Bb = Bm + (size_t)bh * N_ * D_;
    for (int i = tid; i < N_*D_; i += 256) {
        int m = i >> 6, kk = i & 63;
        Bl[m*65 + kk] = Bb[i];
    }
    for (int i = tid; i < 32*64; i += 256) {
        int m = i >> 6, kk = i & 63;
        int r = r0 + m;
        Al[m*65 + kk] = (r < N_) ? Ab[(size_t)r*64 + kk] : 0.f;
    }
    __syncthreads();
    const int w = tid >> 6, l = tid & 63;
    int  mc[4];
    bool mv[4];
    #pragma unroll
    for (int c = 0; c < 4; c++) {
        int m = l + 64*c;
        mv[c] = (m < N_);
        mc[c] = mv[c] ? m : (N_-1);
    }
    float acc[8][4] = {};
    for (int kk = 0; kk < 64; ++kk) {
        float a[8];
        #pragma unroll
        for (int i = 0; i < 8; i++) a[i] = Al[(w*8 + i)*65 + kk];
        float b[4];
        #pragma unroll
        for (int c = 0; c < 4; c++) b[c] = Bl[mc[c]*65 + kk];
        #pragma unroll
        for (int i = 0; i < 8; i++)
            #pragma unroll
            for (int c = 0; c < 4; c++) acc[i][c] += a[i] * b[c];
    }
    #pragma unroll
    for (int i = 0; i < 8; i++) {
        int r = r0 + w*8 + i;
        if (r >= N_) break;
        float* Srow = S + ((size_t)bh*N_ + r) * N_;
        #pragma unroll
        for (int c = 0; c < 4; c++)
            if (mv[c]) Srow[l + 64*c] = acc[i][c] * SCALE;
    }
}

// ---------------------------------------------------------------------------
// K3: in-place row softmax (rows of length 197). 4 rows/block.
__global__ __launch_bounds__(256) void softmax_inplace(float* __restrict__ S) {
    const int row = blockIdx.x*4 + (threadIdx.x >> 6);
    const int l   = threadIdx.x & 63;
    float* p = S + (size_t)row * N_;
    float vv[4];
    float mx = -1e30f;
    #pragma unroll
    for (int c = 0; c < 4; c++) {
        int m = l + 64*c;
        vv[c] = (m < N_) ? p[m] : -1e30f;
        mx = fmaxf(mx, vv[c]);
    }
    #pragma unroll
    for (int off = 32; off; off >>= 1) mx = fmaxf(mx, __shfl_xor(mx, off));
    float s = 0.f;
    #pragma unroll
    for (int c = 0; c < 4; c++) {
        int m = l + 64*c;
        if (m < N_) { vv[c] = __expf(vv[c] - mx); s += vv[c]; }
    }
    #pragma unroll
    for (int off = 32; off; off >>= 1) s += __shfl_xor(s, off);
    const float inv = 1.f / s;
    #pragma unroll
    for (int c = 0; c < 4; c++) {
        int m = l + 64*c;
        if (m < N_) p[m] = vv[c] * inv;
    }
}

// ---------------------------------------------------------------------------
// K4: probs = softmax(conv_l(scores)) fused, one block per (b,n).
__global__ __launch_bounds__(256) void convl_softmax(const float* __restrict__ SC,
        const float* __restrict__ wl, float* __restrict__ PR) {
    __shared__ float raw[12*200];
    __shared__ float mixed[12*200];
    __shared__ float wls[144];
    const int tid = threadIdx.x;
    const int b = blockIdx.x / N_;
    const int n = blockIdx.x - b * N_;
    if (tid < 144) wls[tid] = wl[tid];
    for (int i = tid; i < 12*N_; i += 256) {
        int h = i / N_, m = i - h*N_;
        raw[h*200 + m] = SC[(((size_t)(b*12 + h))*N_ + n)*N_ + m];
    }
    __syncthreads();
    for (int i = tid; i < 12*N_; i += 256) {
        int o = i / N_, m = i - o*N_;
        float s = 0.f;
        #pragma unroll
        for (int h = 0; h < 12; h++) s += wls[o*12 + h] * raw[h*200 + m];
        mixed[o*200 + m] = s;
    }
    __syncthreads();
    const int w = tid >> 6, l = tid & 63;
    for (int j = 0; j < 3; j++) {
        const int o = w*3 + j;
        float vv[4];
        float mx = -1e30f;
        #pragma unroll
        for (int c = 0; c < 4; c++) {
            int m = l + 64*c;
            vv[c] = (m < N_) ? mixed[o*200 + m] : -1e30f;
            mx = fmaxf(mx, vv[c]);
        }
        #pragma unroll
        for (int off = 32; off; off >>= 1) mx = fmaxf(mx, __shfl_xor(mx, off));
        float s = 0.f;
        #pragma unroll
        for (int c = 0; c < 4; c++) {
            int m = l + 64*c;
            if (m < N_) { vv[c] = __expf(vv[c] - mx); s += vv[c]; }
        }
        #pragma unroll
        for (int off = 32; off; off >>= 1) s += __shfl_xor(s, off);
        const float inv = 1.f / s;
        float* Prow = PR + (((size_t)(b*12 + o))*N_ + n)*N_;
        #pragma unroll
        for (int c = 0; c < 4; c++) {
            int m = l + 64*c;
            if (m < N_) Prow[m] = vv[c] * inv;
        }
    }
}

// ---------------------------------------------------------------------------
// K5: attn_w = conv_w(probs) — 12x12 head mix, bf16 output.
__global__ __launch_bounds__(256) void convw_kernel(const float* __restrict__ PR,
        const float* __restrict__ ww, __bf16* __restrict__ AW) {
    __shared__ float wws[144];
    const int tid = threadIdx.x;
    if (tid < 144) wws[tid] = ww[tid];
    __syncthreads();
    const int b = blockIdx.y;
    const long long p = (long long)blockIdx.x * 256 + tid;
    if (p >= NN_) return;
    float in[12];
    #pragma unroll
    for (int h = 0; h < 12; h++) in[h] = PR[((size_t)(b*12 + h))*NN_ + p];
    #pragma unroll
    for (int o = 0; o < 12; o++) {
        float s = 0.f;
        #pragma unroll
        for (int h = 0; h < 12; h++) s += wws[o*12 + h] * in[h];
        AW[((size_t)(b*12 + o))*NN_ + p] = (__bf16)s;
    }
}

// ---------------------------------------------------------------------------
// K6: OPb[b,n,h,d] = sum_m attn_w[b,h,n,m] * v[b,h,m,d]. bf16 aw in, bf16 out.
__global__ __launch_bounds__(256) void av_kernel(const __bf16* __restrict__ AW,
        const float* __restrict__ V, __bf16* __restrict__ OP) {
    __shared__ float Vl[197*64];
    const int tid = threadIdx.x;
    const int bh  = blockIdx.y;
    const int r0  = blockIdx.x * 32;
    const float* Vb = V + (size_t)bh * N_ * D_;
    for (int i = tid; i < N_*D_; i += 256) Vl[i] = Vb[i];
    __syncthreads();
    const int w = tid >> 6, l = tid & 63;
    const __bf16* Arow[8];
    #pragma unroll
    for (int i = 0; i < 8; i++) {
        int r = r0 + w*8 + i;
        if (r >= N_) r = N_ - 1;
        Arow[i] = AW + ((size_t)bh*N_ + r) * N_;
    }
    float acc[8] = {};
    for (int m = 0; m < N_; m++) {
        float bv = Vl[m*64 + l];
        #pragma unroll
        for (int i = 0; i < 8; i++) acc[i] += (float)Arow[i][m] * bv;
    }
    const int b = bh / 12, h = bh - b*12;
    #pragma unroll
    for (int i = 0; i < 8; i++) {
        int r = r0 + w*8 + i;
        if (r < N_)
            OP[((size_t)(b*N_ + r))*C_ + h*64 + l] = (__bf16)acc[i];
    }
}

// ---------------------------------------------------------------------------
extern "C" void kernel_launch(void* const* d_in, const int* in_sizes, int n_in,
                              void* d_out, int out_size, void* d_ws, size_t ws_size,
                              hipStream_t stream) {
    const float* x      = (const float*)d_in[0];
    const float* w_qkv  = (const float*)d_in[1];
    const float* w_proj = (const float*)d_in[2];
    const float* b_proj = (const float*)d_in[3];
    const float* w_cl   = (const float*)d_in[4];
    const float* w_cw   = (const float*)d_in[5];

    float* out    = (float*)d_out;                    // [B,N,C]
    float* scores = out    + (size_t)M_ * C_;         // [B,H,N,N]
    float* probs  = scores + (size_t)BH_ * NN_;       // [B,H,N,N]
    float* vmap   = probs  + (size_t)BH_ * NN_;       // [B,H,N,N]

    char* base = (char*)d_ws;
    const size_t QS = (size_t)BH_ * N_ * D_;          // 4,841,472 floats
    float*  q   = (float*)base;                       // dead after qkt
    float*  k   = q + QS;                             // dead after qkt
    float*  v   = k + QS;                             // live through av
    __bf16* Xb  = (__bf16*)(base + 3*QS*4);           // [6400,768]; dead after mfma_qkv
    __bf16* OPb = Xb;                                 // alias (written by av)
    __bf16* Wqt = (__bf16*)(base + 3*QS*4 + (size_t)MPAD_*768*2);   // [2304,768]
    __bf16* Wpt = Wqt + (size_t)K3_*768;                            // [768,768]
    __bf16* awb = (__bf16*)base;                      // alias q+k region (29.8MB<38.7MB)

    cast_x_kernel <<<(MPAD_*768/4 + 255)/256, 256, 0, stream>>>(x, Xb);
    transpose_cast<<<dim3(72, 24),  256, 0, stream>>>(w_qkv,  Wqt, 768, K3_);
    transpose_cast<<<dim3(24, 24),  256, 0, stream>>>(w_proj, Wpt, 768, 768);

    mfma_qkv      <<<dim3(50, 18),  256, 0, stream>>>(Xb, Wqt, q, k, v);
    qkt_kernel    <<<dim3(7, BH_),  256, 0, stream>>>(q, k, scores);
    qkt_kernel    <<<dim3(7, BH_),  256, 0, stream>>>(v, v, vmap);
    softmax_inplace<<<(BH_*N_)/4,   256, 0, stream>>>(vmap);
    convl_softmax <<<M_,            256, 0, stream>>>(scores, w_cl, probs);
    convw_kernel  <<<dim3(152, B_), 256, 0, stream>>>(probs, w_cw, awb);
    av_kernel     <<<dim3(7, BH_),  256, 0, stream>>>(awb, v, OPb);
    mfma_proj     <<<dim3(50, 6),   256, 0, stream>>>(OPb, Wpt, b_proj, out);
}

// Round 3
// 393.331 us; speedup vs baseline: 2.5400x; 1.7480x over previous
//
#include <hip/hip_runtime.h>
#include <cmath>

#define B_ 32
#define N_ 197
#define C_ 768
#define H_ 12
#define D_ 64
#define M_ (B_*N_)        // 6304
#define MPAD_ 6400        // padded rows for 128-tiles
#define K3_ (3*C_)        // 2304
#define NN_ (N_*N_)       // 38809
#define BH_ (B_*H_)       // 384
#define NP_ 208           // 13*16 row pad
#define KP_ 224           // 7*32 k pad for av
#define SCALE 0.125f

typedef __bf16 bf16x8 __attribute__((ext_vector_type(8)));
typedef __bf16 bf16x4 __attribute__((ext_vector_type(4)));
typedef float  f32x4  __attribute__((ext_vector_type(4)));

__device__ __forceinline__ void gl_lds16(const void* g, void* l) {
    __builtin_amdgcn_global_load_lds(
        (const __attribute__((address_space(1))) void*)g,
        (__attribute__((address_space(3))) void*)l,
        16, 0, 0);
}

// ---------------------------------------------------------------------------
// cast X [6304,768] f32 -> Xb [6400,768] bf16 (pad rows zeroed)
__global__ __launch_bounds__(256) void cast_x_kernel(const float* __restrict__ X,
        __bf16* __restrict__ Xb) {
    const long long i = ((long long)blockIdx.x * 256 + threadIdx.x) * 4;
    if (i >= (long long)MPAD_ * 768) return;
    bf16x4 o;
    if (i < (long long)M_ * 768) {
        float4 f = *(const float4*)&X[i];
        o.x = (__bf16)f.x; o.y = (__bf16)f.y; o.z = (__bf16)f.z; o.w = (__bf16)f.w;
    } else {
        o.x = o.y = o.z = o.w = (__bf16)0.f;
    }
    *(bf16x4*)&Xb[i] = o;
}

// ---------------------------------------------------------------------------
// transpose-cast W [R,Ccols] f32 -> Wt [Ccols,R] bf16
__global__ __launch_bounds__(256) void transpose_cast(const float* __restrict__ W,
        __bf16* __restrict__ Wt, int R, int Ccols) {
    __shared__ float t[32][33];
    const int c0 = blockIdx.x * 32;
    const int r0 = blockIdx.y * 32;
    const int tx = threadIdx.x & 31, ty = threadIdx.x >> 5;
    #pragma unroll
    for (int i = ty; i < 32; i += 8)
        t[i][tx] = W[(size_t)(r0 + i) * Ccols + c0 + tx];
    __syncthreads();
    #pragma unroll
    for (int i = ty; i < 32; i += 8)
        Wt[(size_t)(c0 + i) * R + r0 + tx] = (__bf16)t[tx][i];
}

// ---------------------------------------------------------------------------
// MFMA GEMM: Xb[M,768] @ Wt[2304,768]^T -> scatter to q,k,v BF16 [B,H,N,D]
__global__ __launch_bounds__(256) void mfma_qkv(const __bf16* __restrict__ Xb,
        const __bf16* __restrict__ Wt, __bf16* __restrict__ q,
        __bf16* __restrict__ k, __bf16* __restrict__ v) {
    __shared__ __bf16 As[128*32];
    __shared__ __bf16 Bs[128*32];
    const int tid = threadIdx.x;
    const int wv = tid >> 6, ln = tid & 63;
    const int R0 = blockIdx.x * 128;
    const int C0 = blockIdx.y * 128;
    const int wm = wv >> 1, wn = wv & 1;
    const int arow = ln >> 2, akg = ln & 3;
    f32x4 acc[4][4] = {};
    for (int k0 = 0; k0 < 768; k0 += 32) {
        __syncthreads();
        #pragma unroll
        for (int s = 0; s < 2; s++) {
            const int seg = wv + s*4;
            const int row = seg*16 + arow;
            gl_lds16(Xb + (size_t)(R0 + row)*768 + k0 + akg*8,
                     (char*)As + seg*1024 + ln*16);
            gl_lds16(Wt + (size_t)(C0 + row)*768 + k0 + akg*8,
                     (char*)Bs + seg*1024 + ln*16);
        }
        __syncthreads();
        bf16x8 af[4], bfr[4];
        #pragma unroll
        for (int t = 0; t < 4; t++) {
            af[t]  = *(const bf16x8*)((const char*)As +
                        (wm*64 + t*16 + (ln & 15))*64 + (ln >> 4)*16);
            bfr[t] = *(const bf16x8*)((const char*)Bs +
                        (wn*64 + t*16 + (ln & 15))*64 + (ln >> 4)*16);
        }
        #pragma unroll
        for (int i = 0; i < 4; i++)
            #pragma unroll
            for (int j = 0; j < 4; j++)
                acc[i][j] = __builtin_amdgcn_mfma_f32_16x16x32_bf16(
                                af[i], bfr[j], acc[i][j], 0, 0, 0);
    }
    const int lr = (ln >> 4) * 4;
    const int lc = ln & 15;
    #pragma unroll
    for (int j = 0; j < 4; j++) {
        const int c = C0 + wn*64 + j*16 + lc;
        const int which = c / 768;
        const int rem = c - which*768;
        const int h = rem >> 6, d = rem & 63;
        __bf16* dst = (which == 0) ? q : ((which == 1) ? k : v);
        #pragma unroll
        for (int i = 0; i < 4; i++) {
            #pragma unroll
            for (int rr = 0; rr < 4; rr++) {
                const int r = R0 + wm*64 + i*16 + lr + rr;
                if (r < M_) {
                    const int bb = r / N_, n = r - bb*N_;
                    dst[(((size_t)(bb*H_ + h))*N_ + n)*64 + d] =
                        (__bf16)acc[i][j][rr];
                }
            }
        }
    }
}

// ---------------------------------------------------------------------------
// MFMA GEMM: out[M,768] = OPb[M,768] @ Wpt[768,768]^T + bias (fp32 out)
__global__ __launch_bounds__(256) void mfma_proj(const __bf16* __restrict__ Ab,
        const __bf16* __restrict__ Wt, const float* __restrict__ bias,
        float* __restrict__ Y) {
    __shared__ __bf16 As[128*32];
    __shared__ __bf16 Bs[128*32];
    const int tid = threadIdx.x;
    const int wv = tid >> 6, ln = tid & 63;
    const int R0 = blockIdx.x * 128;
    const int C0 = blockIdx.y * 128;
    const int wm = wv >> 1, wn = wv & 1;
    const int arow = ln >> 2, akg = ln & 3;
    f32x4 acc[4][4] = {};
    for (int k0 = 0; k0 < 768; k0 += 32) {
        __syncthreads();
        #pragma unroll
        for (int s = 0; s < 2; s++) {
            const int seg = wv + s*4;
            const int row = seg*16 + arow;
            gl_lds16(Ab + (size_t)(R0 + row)*768 + k0 + akg*8,
                     (char*)As + seg*1024 + ln*16);
            gl_lds16(Wt + (size_t)(C0 + row)*768 + k0 + akg*8,
                     (char*)Bs + seg*1024 + ln*16);
        }
        __syncthreads();
        bf16x8 af[4], bfr[4];
        #pragma unroll
        for (int t = 0; t < 4; t++) {
            af[t]  = *(const bf16x8*)((const char*)As +
                        (wm*64 + t*16 + (ln & 15))*64 + (ln >> 4)*16);
            bfr[t] = *(const bf16x8*)((const char*)Bs +
                        (wn*64 + t*16 + (ln & 15))*64 + (ln >> 4)*16);
        }
        #pragma unroll
        for (int i = 0; i < 4; i++)
            #pragma unroll
            for (int j = 0; j < 4; j++)
                acc[i][j] = __builtin_amdgcn_mfma_f32_16x16x32_bf16(
                                af[i], bfr[j], acc[i][j], 0, 0, 0);
    }
    const int lr = (ln >> 4) * 4;
    const int lc = ln & 15;
    #pragma unroll
    for (int j = 0; j < 4; j++) {
        const int c = C0 + wn*64 + j*16 + lc;
        const float bv = bias[c];
        #pragma unroll
        for (int i = 0; i < 4; i++) {
            #pragma unroll
            for (int rr = 0; rr < 4; rr++) {
                const int r = R0 + wm*64 + i*16 + lr + rr;
                if (r < M_) Y[(size_t)r*768 + c] = acc[i][j][rr] + bv;
            }
        }
    }
}

// ---------------------------------------------------------------------------
// qkt: S[bh] = SCALE * Q[bh] @ K[bh]^T, bf16 in, fp32 out. One block per bh.
__global__ __launch_bounds__(256) void qkt_mfma(const __bf16* __restrict__ Q,
        const __bf16* __restrict__ Km, float* __restrict__ S) {
    __shared__ __bf16 Al[NP_*64];
    __shared__ __bf16 Bl[NP_*64];
    const int tid = threadIdx.x, bh = blockIdx.x;
    const int w = tid >> 6, L = tid & 63;
    const __bf16* Qb = Q  + (size_t)bh*N_*D_;
    const __bf16* Kb = Km + (size_t)bh*N_*D_;
    for (int i = tid*8; i < NP_*64; i += 2048) {
        const int row = i >> 6;
        bf16x8 z = {};
        *(bf16x8*)&Al[i] = (row < N_) ? *(const bf16x8*)&Qb[i] : z;
        *(bf16x8*)&Bl[i] = (row < N_) ? *(const bf16x8*)&Kb[i] : z;
    }
    __syncthreads();
    const int lm = L & 15, lg = L >> 4;
    for (int rt = w; rt < 13; rt += 4) {
        const bf16x8 a0 = *(const bf16x8*)&Al[(rt*16+lm)*64 + lg*8];
        const bf16x8 a1 = *(const bf16x8*)&Al[(rt*16+lm)*64 + 32 + lg*8];
        const int rbase = rt*16 + lg*4;
        for (int ct = 0; ct < 13; ct++) {
            const bf16x8 b0 = *(const bf16x8*)&Bl[(ct*16+lm)*64 + lg*8];
            const bf16x8 b1 = *(const bf16x8*)&Bl[(ct*16+lm)*64 + 32 + lg*8];
            f32x4 acc = {};
            acc = __builtin_amdgcn_mfma_f32_16x16x32_bf16(a0, b0, acc, 0, 0, 0);
            acc = __builtin_amdgcn_mfma_f32_16x16x32_bf16(a1, b1, acc, 0, 0, 0);
            const int c = ct*16 + lm;
            if (c < N_) {
                #pragma unroll
                for (int r = 0; r < 4; r++) {
                    const int row = rbase + r;
                    if (row < N_)
                        S[((size_t)bh*N_ + row)*N_ + c] = acc[r] * SCALE;
                }
            }
        }
    }
}

// ---------------------------------------------------------------------------
// vvt_softmax: VM[bh] = softmax(SCALE * V V^T) fused. One block per bh.
__global__ __launch_bounds__(256) void vvt_softmax(const __bf16* __restrict__ V,
        float* __restrict__ VM) {
    __shared__ __bf16 Al[NP_*64];
    const int tid = threadIdx.x, bh = blockIdx.x;
    const int w = tid >> 6, L = tid & 63;
    const __bf16* Vb = V + (size_t)bh*N_*D_;
    for (int i = tid*8; i < NP_*64; i += 2048) {
        const int row = i >> 6;
        bf16x8 z = {};
        *(bf16x8*)&Al[i] = (row < N_) ? *(const bf16x8*)&Vb[i] : z;
    }
    __syncthreads();
    const int lm = L & 15, lg = L >> 4;
    for (int rt = w; rt < 13; rt += 4) {
        const bf16x8 a0 = *(const bf16x8*)&Al[(rt*16+lm)*64 + lg*8];
        const bf16x8 a1 = *(const bf16x8*)&Al[(rt*16+lm)*64 + 32 + lg*8];
        f32x4 acc[13];
        for (int ct = 0; ct < 13; ct++) {
            const bf16x8 b0 = *(const bf16x8*)&Al[(ct*16+lm)*64 + lg*8];
            const bf16x8 b1 = *(const bf16x8*)&Al[(ct*16+lm)*64 + 32 + lg*8];
            f32x4 a = {};
            a = __builtin_amdgcn_mfma_f32_16x16x32_bf16(a0, b0, a, 0, 0, 0);
            a = __builtin_amdgcn_mfma_f32_16x16x32_bf16(a1, b1, a, 0, 0, 0);
            acc[ct] = a;
        }
        // scale + mask invalid cols
        float mx[4] = {-1e30f, -1e30f, -1e30f, -1e30f};
        #pragma unroll
        for (int ct = 0; ct < 13; ct++) {
            const bool valid = (ct*16 + lm) < N_;
            #pragma unroll
            for (int r = 0; r < 4; r++) {
                float val = valid ? acc[ct][r] * SCALE : -1e30f;
                acc[ct][r] = val;
                mx[r] = fmaxf(mx[r], val);
            }
        }
        #pragma unroll
        for (int r = 0; r < 4; r++) {
            #pragma unroll
            for (int off = 1; off < 16; off <<= 1)
                mx[r] = fmaxf(mx[r], __shfl_xor(mx[r], off));
        }
        float sm[4] = {0.f, 0.f, 0.f, 0.f};
        #pragma unroll
        for (int ct = 0; ct < 13; ct++)
            #pragma unroll
            for (int r = 0; r < 4; r++) {
                const float e = __expf(acc[ct][r] - mx[r]);
                acc[ct][r] = e;
                sm[r] += e;
            }
        #pragma unroll
        for (int r = 0; r < 4; r++) {
            #pragma unroll
            for (int off = 1; off < 16; off <<= 1)
                sm[r] += __shfl_xor(sm[r], off);
            sm[r] = 1.f / sm[r];
        }
        const int rbase = rt*16 + lg*4;
        for (int ct = 0; ct < 13; ct++) {
            const int c = ct*16 + lm;
            if (c < N_) {
                #pragma unroll
                for (int r = 0; r < 4; r++) {
                    const int row = rbase + r;
                    if (row < N_)
                        VM[((size_t)bh*N_ + row)*N_ + c] = acc[ct][r] * sm[r];
                }
            }
        }
    }
}

// ---------------------------------------------------------------------------
// K4: probs = softmax(conv_l(scores)) fused, one block per (b,n).
__global__ __launch_bounds__(256) void convl_softmax(const float* __restrict__ SC,
        const float* __restrict__ wl, float* __restrict__ PR) {
    __shared__ float raw[12*200];
    __shared__ float mixed[12*200];
    __shared__ float wls[144];
    const int tid = threadIdx.x;
    const int b = blockIdx.x / N_;
    const int n = blockIdx.x - b * N_;
    if (tid < 144) wls[tid] = wl[tid];
    for (int i = tid; i < 12*N_; i += 256) {
        int h = i / N_, m = i - h*N_;
        raw[h*200 + m] = SC[(((size_t)(b*12 + h))*N_ + n)*N_ + m];
    }
    __syncthreads();
    for (int i = tid; i < 12*N_; i += 256) {
        int o = i / N_, m = i - o*N_;
        float s = 0.f;
        #pragma unroll
        for (int h = 0; h < 12; h++) s += wls[o*12 + h] * raw[h*200 + m];
        mixed[o*200 + m] = s;
    }
    __syncthreads();
    const int w = tid >> 6, l = tid & 63;
    for (int j = 0; j < 3; j++) {
        const int o = w*3 + j;
        float vv[4];
        float mx = -1e30f;
        #pragma unroll
        for (int c = 0; c < 4; c++) {
            int m = l + 64*c;
            vv[c] = (m < N_) ? mixed[o*200 + m] : -1e30f;
            mx = fmaxf(mx, vv[c]);
        }
        #pragma unroll
        for (int off = 32; off; off >>= 1) mx = fmaxf(mx, __shfl_xor(mx, off));
        float s = 0.f;
        #pragma unroll
        for (int c = 0; c < 4; c++) {
            int m = l + 64*c;
            if (m < N_) { vv[c] = __expf(vv[c] - mx); s += vv[c]; }
        }
        #pragma unroll
        for (int off = 32; off; off >>= 1) s += __shfl_xor(s, off);
        const float inv = 1.f / s;
        float* Prow = PR + (((size_t)(b*12 + o))*N_ + n)*N_;
        #pragma unroll
        for (int c = 0; c < 4; c++) {
            int m = l + 64*c;
            if (m < N_) Prow[m] = vv[c] * inv;
        }
    }
}

// ---------------------------------------------------------------------------
// K5: attn_w = conv_w(probs), bf16 PADDED output [B,H,197,224].
__global__ __launch_bounds__(256) void convw_kernel(const float* __restrict__ PR,
        const float* __restrict__ ww, __bf16* __restrict__ AW) {
    __shared__ float wws[144];
    const int tid = threadIdx.x;
    if (tid < 144) wws[tid] = ww[tid];
    __syncthreads();
    const int b = blockIdx.y;
    const long long p = (long long)blockIdx.x * 256 + tid;
    if (p >= NN_) return;
    const int n = (int)(p / N_);
    const int m = (int)(p - (long long)n * N_);
    float in[12];
    #pragma unroll
    for (int h = 0; h < 12; h++) in[h] = PR[((size_t)(b*12 + h))*NN_ + p];
    #pragma unroll
    for (int o = 0; o < 12; o++) {
        float s = 0.f;
        #pragma unroll
        for (int h = 0; h < 12; h++) s += wws[o*12 + h] * in[h];
        AW[((size_t)(b*12 + o)*N_ + n)*KP_ + m] = (__bf16)s;
    }
}

// ---------------------------------------------------------------------------
// av: OP[b,n,h*64+d] = sum_m AW[bh,n,m] * V[bh,m,d]. One block per bh.
// A-frags straight from global (padded rows); V transposed into LDS
// with zeroed pad cols (annihilates AW's garbage pad).
__global__ __launch_bounds__(256) void av_mfma(const __bf16* __restrict__ AW,
        const __bf16* __restrict__ V, __bf16* __restrict__ OP) {
    __shared__ __bf16 Vt[64*KP_];
    const int tid = threadIdx.x, bh = blockIdx.x;
    const int w = tid >> 6, L = tid & 63;
    for (int i = tid*8; i < 64*KP_; i += 2048) {
        bf16x8 z = {};
        *(bf16x8*)&Vt[i] = z;
    }
    __syncthreads();
    const __bf16* Vb = V + (size_t)bh*N_*D_;
    for (int i = tid*8; i < N_*D_; i += 2048) {
        const int row = i >> 6, col = i & 63;
        const bf16x8 vv = *(const bf16x8*)&Vb[i];
        #pragma unroll
        for (int j = 0; j < 8; j++) Vt[(col+j)*KP_ + row] = vv[j];
    }
    __syncthreads();
    const int lm = L & 15, lg = L >> 4;
    const int b = bh / H_, h = bh - b*H_;
    const __bf16* Ab = AW + (size_t)bh*N_*KP_;
    for (int rt = w; rt < 13; rt += 4) {
        int ar = rt*16 + lm;
        if (ar >= N_) ar = 0;   // clamp: results for pad rows are discarded
        f32x4 acc[4] = {};
        for (int k0 = 0; k0 < KP_; k0 += 32) {
            const bf16x8 a = *(const bf16x8*)&Ab[(size_t)ar*KP_ + k0 + lg*8];
            #pragma unroll
            for (int ct = 0; ct < 4; ct++) {
                const bf16x8 bf = *(const bf16x8*)&Vt[(ct*16+lm)*KP_ + k0 + lg*8];
                acc[ct] = __builtin_amdgcn_mfma_f32_16x16x32_bf16(
                              a, bf, acc[ct], 0, 0, 0);
            }
        }
        const int rbase = rt*16 + lg*4;
        #pragma unroll
        for (int ct = 0; ct < 4; ct++) {
            const int d = ct*16 + lm;
            #pragma unroll
            for (int r = 0; r < 4; r++) {
                const int row = rbase + r;
                if (row < N_)
                    OP[((size_t)(b*N_ + row))*C_ + h*64 + d] = (__bf16)acc[ct][r];
            }
        }
    }
}

// ---------------------------------------------------------------------------
extern "C" void kernel_launch(void* const* d_in, const int* in_sizes, int n_in,
                              void* d_out, int out_size, void* d_ws, size_t ws_size,
                              hipStream_t stream) {
    const float* x      = (const float*)d_in[0];
    const float* w_qkv  = (const float*)d_in[1];
    const float* w_proj = (const float*)d_in[2];
    const float* b_proj = (const float*)d_in[3];
    const float* w_cl   = (const float*)d_in[4];
    const float* w_cw   = (const float*)d_in[5];

    float* out    = (float*)d_out;                    // [B,N,C]
    float* scores = out    + (size_t)M_ * C_;         // [B,H,N,N]
    float* probs  = scores + (size_t)BH_ * NN_;       // [B,H,N,N]
    float* vmap   = probs  + (size_t)BH_ * NN_;       // [B,H,N,N]

    char* base = (char*)d_ws;
    const size_t QS = (size_t)BH_ * N_ * D_;          // elements per q/k/v
    __bf16* q   = (__bf16*)base;                      // 9.68 MB
    __bf16* k   = q + QS;
    __bf16* v   = k + QS;
    __bf16* Xb  = v + QS;                             // [6400,768] 9.8 MB
    __bf16* OPb = Xb;                                 // alias (pad rows stay 0)
    __bf16* Wqt = Xb + (size_t)MPAD_*768;             // [2304,768]
    __bf16* Wpt = Wqt + (size_t)K3_*768;              // [768,768]
    __bf16* aw  = Wpt + (size_t)768*768;              // [B,H,197,224] 33.9 MB

    cast_x_kernel <<<(MPAD_*768/4 + 255)/256, 256, 0, stream>>>(x, Xb);
    transpose_cast<<<dim3(72, 24),  256, 0, stream>>>(w_qkv,  Wqt, 768, K3_);
    transpose_cast<<<dim3(24, 24),  256, 0, stream>>>(w_proj, Wpt, 768, 768);

    mfma_qkv      <<<dim3(50, 18),  256, 0, stream>>>(Xb, Wqt, q, k, v);
    qkt_mfma      <<<BH_,           256, 0, stream>>>(q, k, scores);
    vvt_softmax   <<<BH_,           256, 0, stream>>>(v, vmap);
    convl_softmax <<<M_,            256, 0, stream>>>(scores, w_cl, probs);
    convw_kernel  <<<dim3(152, B_), 256, 0, stream>>>(probs, w_cw, aw);
    av_mfma       <<<BH_,           256, 0, stream>>>(aw, v, OPb);
    mfma_proj     <<<dim3(50, 6),   256, 0, stream>>>(OPb, Wpt, b_proj, out);
}